// Round 7
// baseline (110.001 us; speedup 1.0000x reference)
//
#include <hip/hip_runtime.h>
#include <stdint.h>

#define T_LEN 512
#define I_LEN 5
#define CHUNK 8                    // timesteps per staged chunk
#define NCHUNK (T_LEN / CHUNK)     // 64

// ---- DPP helpers (conventions verified rounds 1-5) -------------------------
// XOR-pattern DPP for the final fc reduce (row-local involutions):
//   0xB1 -> lane^1, 0x4E -> lane^2, 0x141 -> lane^7, 0x140 -> lane^15
template<int CTRL>
__device__ __forceinline__ float fdpp(float x) {
    return __int_as_float(__builtin_amdgcn_update_dpp(
        0, __float_as_int(x), CTRL, 0xF, 0xF, true));
}

// Guaranteed single-instruction DPP fmac: acc += rot_k(h) * w.
// row_ror:k delivers lane (i-k)&15 within each 16-lane row (verified r5:
// pairing weight W_hh[j][(j-k)&15] gives absmax 0).
#define FMAC_DPP(acc, hv, w, KSTR)                                          \
    asm("v_fmac_f32_dpp %0, %1, %2 row_ror:" KSTR                           \
        " row_mask:0xf bank_mask:0xf"                                       \
        : "+v"(acc) : "v"(hv), "v"(w))

// tanh with pre-scaled input: zs = 2*log2(e)*z -> tanh(z)
__device__ __forceinline__ float tanh_pre(float zs) {
    float e = __builtin_exp2f(zs);
    float rc = __builtin_amdgcn_rcpf(e + 1.0f);
    return __builtin_fmaf(-2.0f, rc, 1.0f);   // saturates correctly
}

// global -> LDS direct DMA, 16B/lane, LDS dst = wave-uniform base + lane*16
__device__ __forceinline__ void gload_lds16(const float* g, float* l) {
    auto gp = reinterpret_cast<const __attribute__((address_space(1))) float*>(
        reinterpret_cast<uintptr_t>(g));
    auto lp = reinterpret_cast<__attribute__((address_space(3))) float*>(
        reinterpret_cast<uintptr_t>(l));
    __builtin_amdgcn_global_load_lds(gp, lp, 16, 0, 0);
}

// Volatile asm ds_read_b128: cannot be sunk or split by the scheduler.
#define DSR(dst, addr, OFFSTR)                                              \
    asm volatile("ds_read_b128 %0, %1 offset:" OFFSTR                       \
                 : "=v"(dst) : "v"(addr))

// r7 FIX: contiguous per-batch layout -> 16-byte stride (was 64 in r6: that
// read scrambled x and caused the 0.32 absmax failure).
#define DSR10(q, addr)                                                      \
    do {                                                                    \
        DSR((q)[0], (addr), "0");   DSR((q)[1], (addr), "16");              \
        DSR((q)[2], (addr), "32");  DSR((q)[3], (addr), "48");              \
        DSR((q)[4], (addr), "64");  DSR((q)[5], (addr), "80");              \
        DSR((q)[6], (addr), "96");  DSR((q)[7], (addr), "112");             \
        DSR((q)[8], (addr), "128"); DSR((q)[9], (addr), "144");             \
    } while (0)

#define WAIT_LGKM0()                                                        \
    do {                                                                    \
        asm volatile("s_waitcnt lgkmcnt(0)" ::: "memory");                  \
        __builtin_amdgcn_sched_barrier(0);                                  \
    } while (0)

#define WAIT_VM(N)                                                          \
    asm volatile("s_waitcnt vmcnt(" #N ")" ::: "memory")

// Component extract with compile-time-constant idx (folds after unroll).
__device__ __forceinline__ float f4_at(const float4* b, int idx) {
    const float4 v = b[idx >> 2];
    switch (idx & 3) {
        case 0: return v.x;
        case 1: return v.y;
        case 2: return v.z;
        default: return v.w;
    }
}

// 8 timesteps. Two 16-lane rows cooperate per batch:
//   row A (r=0): proj i=0..2 + bias + recurrent k=0..7
//   row B (r=1): proj i=3..4 + recurrent k=8..15 (h held pre-rotated by 8)
// Cross-row combine: ds_swizzle lane^16 (offset 0x401f) + add.
__device__ __forceinline__ void steps8(const float4* __restrict__ q, float& hv,
                                       const float* __restrict__ wi,
                                       const float* __restrict__ whh,
                                       float bias) {
#pragma unroll
    for (int s = 0; s < 8; ++s) {
        const float x0 = f4_at(q, 5 * s + 0);
        const float x1 = f4_at(q, 5 * s + 1);
        const float x2 = f4_at(q, 5 * s + 2);
        const float x3 = f4_at(q, 5 * s + 3);
        const float x4 = f4_at(q, 5 * s + 4);

        // projection (zero-padded weights make this row-uniform code)
        float p1 = __builtin_fmaf(x0, wi[0], bias);
        p1 = __builtin_fmaf(x1, wi[1], p1);
        p1 = __builtin_fmaf(x2, wi[2], p1);
        float p2 = x3 * wi[3];
        p2 = __builtin_fmaf(x4, wi[4], p2);

        // m=0: own-held value (row A: h_j ; row B: h_{j+8}), no DPP
        float c = __builtin_fmaf(hv, whh[0], p2);

        // m=1..7: single-instruction DPP fmacs, alternating accumulators
        FMAC_DPP(p1, hv, whh[1], "1");
        FMAC_DPP(c,  hv, whh[2], "2");
        FMAC_DPP(p1, hv, whh[3], "3");
        FMAC_DPP(c,  hv, whh[4], "4");
        FMAC_DPP(p1, hv, whh[5], "5");
        FMAC_DPP(c,  hv, whh[6], "6");
        FMAC_DPP(p1, hv, whh[7], "7");

        float z = p1 + c;

        // cross-row exchange: lane j <-> lane j^16 (BitMode 0x401f, ISA doc)
        float zt;
        asm volatile("ds_swizzle_b32 %0, %1 offset:0x401f\n\t"
                     "s_waitcnt lgkmcnt(0)"
                     : "=v"(zt) : "v"(z));
        z += zt;

        hv = tanh_pre(z);

        // row B (rows 1,3 of the wave) re-rotates h by 8 in place; rows 0,2
        // preserved by row_mask. s_nop guards VALU-write -> DPP-read hazard.
        asm volatile("s_nop 1\n\t"
                     "v_mov_b32_dpp %0, %0 row_ror:8 row_mask:0xa "
                     "bank_mask:0xf\n\t"
                     "s_nop 1"
                     : "+v"(hv));
    }
}

__global__ __launch_bounds__(256, 4) void rnn_m2o_kernel(
    const float* __restrict__ x, const float* __restrict__ W_ih,
    const float* __restrict__ W_hh, const float* __restrict__ b_ih,
    const float* __restrict__ b_hh, const float* __restrict__ W_fc,
    const float* __restrict__ b_fc, float* __restrict__ out)
{
    const int tid  = threadIdx.x;
    const int wave = tid >> 6;         // 0..3
    const int lane = tid & 63;
    const int j    = lane & 15;        // hidden unit owned by this lane
    const int r    = (lane >> 4) & 1;  // 0 = row A, 1 = row B
    const int half = (lane >> 5) & 1;  // which of the wave's 2 batches

    // [wave][slot][256 dwords]; per slot: batch0 chunk at bytes 0..159,
    // batch1 at 160..319 (from linear lane*16B writes of the staging map).
    __shared__ float lds_x[4][4][256];

    // fold tanh's 2*log2(e) input scale into all pre-activation weights
    const float SC = 2.8853900817779268f;

    // zero-padded projection weights (row-uniform inner loop)
    float wi[5];
    wi[0] = r ? 0.0f : W_ih[j * 5 + 0] * SC;
    wi[1] = r ? 0.0f : W_ih[j * 5 + 1] * SC;
    wi[2] = r ? 0.0f : W_ih[j * 5 + 2] * SC;
    wi[3] = r ? W_ih[j * 5 + 3] * SC : 0.0f;
    wi[4] = r ? W_ih[j * 5 + 4] * SC : 0.0f;
    const float bias = r ? 0.0f : (b_ih[j] + b_hh[j]) * SC;

    // whh[m] pairs with ror:m of the held value; row B covers k=m+8 via its
    // pre-rotated copy (+8 == -8 mod 16):  whh[m] = W_hh[j][(j-m+8r)&15]
    float whh[8];
#pragma unroll
    for (int m = 0; m < 8; ++m)
        whh[m] = W_hh[j * 16 + ((j - m + 8 * r + 16) & 15)] * SC;

    // row B holds h rotated by 8 at loop end -> pair fc weight accordingly
    const float wfc = W_fc[(j + 8 * r) & 15];
    const float bfc = b_fc[0];

    const int bb = blockIdx.x * 8 + wave * 2;   // wave's first batch

    // staging map: lanes 0-9 -> batch bb f4#lane; 10-19 -> bb+1 f4#(lane-10);
    // lanes >= 20 load a harmless duplicate (slot bytes 320+ are unused).
    int fidx, bo;
    if (lane < 10)      { fidx = lane;      bo = 0; }
    else if (lane < 20) { fidx = lane - 10; bo = 1; }
    else                { fidx = 0;         bo = 0; }
    const float* gsrc = x + (size_t)(bb + bo) * (T_LEN * I_LEN) + fidx * 4;

    // compute-read base: my batch's 160-byte region within the slot
    const uint32_t lds_base =
        (uint32_t)(uintptr_t)&lds_x[wave][0][0] + (uint32_t)(half * 160);

    // Prologue: stage chunks 0..2 into slots 0..2.
    gload_lds16(gsrc + 0 * (CHUNK * I_LEN), &lds_x[wave][0][0]);
    gload_lds16(gsrc + 1 * (CHUNK * I_LEN), &lds_x[wave][1][0]);
    gload_lds16(gsrc + 2 * (CHUNK * I_LEN), &lds_x[wave][2][0]);

    float hv = 0.0f;
    float4 q[10];

    for (int n = 0; n < NCHUNK; ++n) {
        // issue chunk n+3 (wraps to harmless dummy reloads at the tail)
        const int cpf = (n + 3) & (NCHUNK - 1);
        gload_lds16(gsrc + cpf * (CHUNK * I_LEN),
                    &lds_x[wave][(n + 3) & 3][0]);
        WAIT_VM(3);                   // chunk n landed (3 newer in flight)
        DSR10(q, lds_base + (uint32_t)((n & 3) * 1024));
        WAIT_LGKM0();                 // q valid (rule #18 fence)
        steps8(q, hv, wi, whh, bias);
    }
    WAIT_VM(0);                       // drain tail DMAs before endpgm

    // fc + sigmoid: row-local 16-lane reduce (both rows hold a consistent
    // (h, wfc) pairing); lane 0 of each 32-half writes its batch.
    float rr = hv * wfc;
    rr += fdpp<0xB1>(rr);
    rr += fdpp<0x4E>(rr);
    rr += fdpp<0x141>(rr);
    rr += fdpp<0x140>(rr);
    if ((lane & 31) == 0) {
        float z = rr + bfc;
        float sg = __builtin_amdgcn_rcpf(
            1.0f + __builtin_exp2f(z * -1.4426950408889634f));
        out[bb + half] = sg;
    }
}

extern "C" void kernel_launch(void* const* d_in, const int* in_sizes, int n_in,
                              void* d_out, int out_size, void* d_ws, size_t ws_size,
                              hipStream_t stream) {
    const float* x    = (const float*)d_in[0];
    const float* W_ih = (const float*)d_in[1];
    const float* W_hh = (const float*)d_in[2];
    const float* b_ih = (const float*)d_in[3];
    const float* b_hh = (const float*)d_in[4];
    const float* W_fc = (const float*)d_in[5];
    const float* b_fc = (const float*)d_in[6];
    float* out = (float*)d_out;

    const int B = in_sizes[0] / (T_LEN * I_LEN);   // 8192
    const int blocks = B / 8;                      // 8 batches / block
    rnn_m2o_kernel<<<blocks, 256, 0, stream>>>(x, W_ih, W_hh, b_ih, b_hh,
                                               W_fc, b_fc, out);
}

// Round 9
// 74.883 us; speedup vs baseline: 1.4690x; 1.4690x over previous
//
#include <hip/hip_runtime.h>
#include <stdint.h>

#define T_LEN 512
#define I_LEN 5
#define CHUNK 8                    // timesteps per staged chunk
#define NCHUNK 64                  // T_LEN / CHUNK

// __fp16 matches __builtin_amdgcn_cvt_pkrtz's return element type (r8 fix)
typedef __fp16 h2_t __attribute__((ext_vector_type(2)));
typedef __fp16 h4_t __attribute__((ext_vector_type(4)));
typedef float  f4v  __attribute__((ext_vector_type(4)));

// global -> LDS direct DMA, 16B/lane, LDS dst = wave-uniform base + lane*16
__device__ __forceinline__ void gload_lds16(const float* g, float* l) {
    auto gp = reinterpret_cast<const __attribute__((address_space(1))) float*>(
        reinterpret_cast<uintptr_t>(g));
    auto lp = reinterpret_cast<__attribute__((address_space(3))) float*>(
        reinterpret_cast<uintptr_t>(l));
    __builtin_amdgcn_global_load_lds(gp, lp, 16, 0, 0);
}

// Volatile asm ds_read_b128: cannot be sunk or split by the scheduler.
#define DSR(dst, addr, OFFSTR)                                              \
    asm volatile("ds_read_b128 %0, %1 offset:" OFFSTR                       \
                 : "=v"(dst) : "v"(addr))

// One batch-row chunk: 10 float4 at 16B stride (row is 176B-strided, aligned)
#define DSR10(q, addr)                                                      \
    do {                                                                    \
        DSR((q)[0], (addr), "0");   DSR((q)[1], (addr), "16");              \
        DSR((q)[2], (addr), "32");  DSR((q)[3], (addr), "48");              \
        DSR((q)[4], (addr), "64");  DSR((q)[5], (addr), "80");              \
        DSR((q)[6], (addr), "96");  DSR((q)[7], (addr), "112");             \
        DSR((q)[8], (addr), "128"); DSR((q)[9], (addr), "144");             \
    } while (0)

#define WAIT_LGKM0()                                                        \
    do {                                                                    \
        asm volatile("s_waitcnt lgkmcnt(0)" ::: "memory");                  \
        __builtin_amdgcn_sched_barrier(0);                                  \
    } while (0)

#define WAIT_VM(N)                                                          \
    asm volatile("s_waitcnt vmcnt(" #N ")" ::: "memory")

// Component extract with compile-time-constant idx (folds after unroll).
__device__ __forceinline__ float f4_at(const float4* b, int idx) {
    const float4 v = b[idx >> 2];
    switch (idx & 3) {
        case 0: return v.x;
        case 1: return v.y;
        case 2: return v.z;
        default: return v.w;
    }
}

// tanh with pre-scaled input: zs = 2*log2(e)*z -> tanh(z); saturates right.
__device__ __forceinline__ float tanh_pre(float zs) {
    float e  = __builtin_exp2f(zs);
    float rc = __builtin_amdgcn_rcpf(e + 1.0f);
    return __builtin_fmaf(-2.0f, rc, 1.0f);
}

// 8 timesteps for 16 batches on one wave, via two 16x16x16 f16 MFMAs/step.
//   xw = W_ih_pad * x_t + bias   (off the serial chain)
//   z  = W_hh * h + xw ; h = tanh(z)
// Key invariant: D(row=4g+r) grouping == B(k=4g+i) grouping, so
// tanh(D) --cvt_pkrtz--> next B fragment with ZERO cross-lane movement.
__device__ __forceinline__ void steps8(const float4* __restrict__ q,
                                       h4_t& bh, f4v& hf,
                                       h4_t ahh, h4_t aih, f4v cbias) {
#pragma unroll
    for (int s = 0; s < 8; ++s) {
        // x extraction is lane-uniform: odd lane-groups read LDS at +16B,
        // so their element 5s+0 is x4 (their only live B1 slot, k=4).
        const float e0 = f4_at(q, 5 * s + 0);
        const float e1 = f4_at(q, 5 * s + 1);
        const float e2 = f4_at(q, 5 * s + 2);
        const float e3 = f4_at(q, 5 * s + 3);
        h2_t lo = __builtin_amdgcn_cvt_pkrtz(e0, e1);
        h2_t hi = __builtin_amdgcn_cvt_pkrtz(e2, e3);
        h4_t b1 = __builtin_shufflevector(lo, hi, 0, 1, 2, 3);

        f4v acc = __builtin_amdgcn_mfma_f32_16x16x16f16(aih, b1, cbias, 0, 0, 0);
        acc = __builtin_amdgcn_mfma_f32_16x16x16f16(ahh, bh, acc, 0, 0, 0);

        const float t0 = tanh_pre(acc[0]);
        const float t1 = tanh_pre(acc[1]);
        const float t2 = tanh_pre(acc[2]);
        const float t3 = tanh_pre(acc[3]);
        hf[0] = t0; hf[1] = t1; hf[2] = t2; hf[3] = t3;

        h2_t blo = __builtin_amdgcn_cvt_pkrtz(t0, t1);
        h2_t bhi = __builtin_amdgcn_cvt_pkrtz(t2, t3);
        bh = __builtin_shufflevector(blo, bhi, 0, 1, 2, 3);
    }
}

__global__ __launch_bounds__(64) void rnn_m2o_kernel(
    const float* __restrict__ x, const float* __restrict__ W_ih,
    const float* __restrict__ W_hh, const float* __restrict__ b_ih,
    const float* __restrict__ b_hh, const float* __restrict__ W_fc,
    const float* __restrict__ b_fc, float* __restrict__ out)
{
    const int lane = threadIdx.x;      // one wave per block
    const int g    = lane >> 4;        // lane-group 0..3
    const int bcol = lane & 15;        // batch column (n of B/D), A row (m)
    const int bb   = blockIdx.x * 16;  // first batch of this wave

    // 4 slots x (16 batches x 44 dwords + DMA-dump pad) = 4 x 3072 B
    __shared__ float lds[4 * 768];

    // Fold tanh's 2*log2(e) input scale into all pre-activation weights.
    const float SC = 2.8853900817779268f;

    // MFMA fragments (A: m=lane&15, k=4g+i ; C/D: n=lane&15, row=4g+r)
    h4_t ahh, aih;
    f4v  cbias, wfc4;
#pragma unroll
    for (int i = 0; i < 4; ++i) {
        const int k = 4 * g + i;
        ahh[i]   = (__fp16)(W_hh[bcol * 16 + k] * SC);
        aih[i]   = (__fp16)((k < I_LEN) ? W_ih[bcol * I_LEN + k] * SC : 0.0f);
        cbias[i] = (b_ih[k] + b_hh[k]) * SC;
        wfc4[i]  = W_fc[k];
    }
    const float bfc = b_fc[0];

    // Staging map: slot index s = 64L + lane; s = 11*b + i (i=0..9 real f4,
    // i=10 pad). Linear lane*16B DMA writes land batch b at dword 44b (+4i):
    // 44-dword batch stride -> 2-way banks on reads (free).
    const float* gsrc[3];
#pragma unroll
    for (int L = 0; L < 3; ++L) {
        const int s = 64 * L + lane;
        const int sb = s / 11, si = s % 11;
        const bool real = (s < 176) && (si < 10);
        gsrc[L] = x + (size_t)(bb + (real ? sb : 0)) * (T_LEN * I_LEN)
                    + (real ? si * 4 : 0);
    }

#define STAGE(n_, slot_)                                                    \
    do {                                                                    \
        const int off_ = (n_) * (CHUNK * I_LEN);                            \
        gload_lds16(gsrc[0] + off_, &lds[(slot_) * 768 + 0]);               \
        gload_lds16(gsrc[1] + off_, &lds[(slot_) * 768 + 256]);             \
        gload_lds16(gsrc[2] + off_, &lds[(slot_) * 768 + 512]);             \
    } while (0)

    // Read base: my batch row (176B stride); odd groups +16B (x4-shift).
    const uint32_t rbase = (uint32_t)(uintptr_t)&lds[0]
                         + (uint32_t)(bcol * 176 + (g & 1) * 16);

    h4_t bh = (h4_t)0;                 // h_0 = 0 (f16 B fragment)
    f4v  hf = (f4v)0;                  // f32 copy of h (for fc at the end)
    float4 qA[10], qB[10];

    // Prologue: stage chunks 0..2, read chunk 0.
    STAGE(0, 0); STAGE(1, 1); STAGE(2, 2);
    WAIT_VM(6);                        // chunk 0 landed
    DSR10(qA, rbase);
    WAIT_LGKM0();

    for (int n = 0; n < NCHUNK; n += 2) {
        {   // even: compute chunk n (qA), prefetch-read chunk n+1
            STAGE((n + 3) & (NCHUNK - 1), (n + 3) & 3);
            WAIT_VM(6);                // chunk n+1 landed
            DSR10(qB, rbase + (uint32_t)(((n + 1) & 3) * 3072));
            steps8(qA, bh, hf, ahh, aih, cbias);
            WAIT_LGKM0();
        }
        {   // odd: compute chunk n+1 (qB), prefetch-read chunk n+2
            STAGE((n + 4) & (NCHUNK - 1), (n + 4) & 3);
            WAIT_VM(6);                // chunk n+2 landed
            DSR10(qA, rbase + (uint32_t)(((n + 2) & 3) * 3072));
            steps8(qB, bh, hf, ahh, aih, cbias);
            WAIT_LGKM0();
        }
    }
    WAIT_VM(0);                        // drain tail DMAs

    // fc + sigmoid: lane partial over its 4 rows, then sum the 4 lane-groups
    float p = hf[0] * wfc4[0] + hf[1] * wfc4[1]
            + hf[2] * wfc4[2] + hf[3] * wfc4[3];
    p += __shfl_xor(p, 16);
    p += __shfl_xor(p, 32);
    if (lane < 16) {
        const float z = p + bfc;
        out[bb + lane] = __builtin_amdgcn_rcpf(
            1.0f + __builtin_exp2f(z * -1.4426950408889634f));
    }
#undef STAGE
}

extern "C" void kernel_launch(void* const* d_in, const int* in_sizes, int n_in,
                              void* d_out, int out_size, void* d_ws, size_t ws_size,
                              hipStream_t stream) {
    const float* x    = (const float*)d_in[0];
    const float* W_ih = (const float*)d_in[1];
    const float* W_hh = (const float*)d_in[2];
    const float* b_ih = (const float*)d_in[3];
    const float* b_hh = (const float*)d_in[4];
    const float* W_fc = (const float*)d_in[5];
    const float* b_fc = (const float*)d_in[6];
    float* out = (float*)d_out;

    const int B = in_sizes[0] / (T_LEN * I_LEN);   // 8192
    const int blocks = B / 16;                     // 16 batches per wave
    rnn_m2o_kernel<<<blocks, 64, 0, stream>>>(x, W_ih, W_hh, b_ih, b_hh,
                                              W_fc, b_fc, out);
}

// Round 10
// 72.593 us; speedup vs baseline: 1.5153x; 1.0315x over previous
//
#include <hip/hip_runtime.h>
#include <stdint.h>

#define T_LEN 512
#define I_LEN 5
#define CHUNK 8                    // timesteps per staged chunk
#define NCHUNK 64                  // T_LEN / CHUNK

// __fp16 matches __builtin_amdgcn_cvt_pkrtz's return element type
typedef __fp16 h2_t __attribute__((ext_vector_type(2)));
typedef __fp16 h4_t __attribute__((ext_vector_type(4)));
typedef float  f4v  __attribute__((ext_vector_type(4)));

// global -> LDS direct DMA, 16B/lane, LDS dst = wave-uniform base + lane*16
__device__ __forceinline__ void gload_lds16(const float* g, float* l) {
    auto gp = reinterpret_cast<const __attribute__((address_space(1))) float*>(
        reinterpret_cast<uintptr_t>(g));
    auto lp = reinterpret_cast<__attribute__((address_space(3))) float*>(
        reinterpret_cast<uintptr_t>(l));
    __builtin_amdgcn_global_load_lds(gp, lp, 16, 0, 0);
}

// Volatile asm ds_read_b128: cannot be sunk or split by the scheduler.
#define DSR(dst, addr, OFFSTR)                                              \
    asm volatile("ds_read_b128 %0, %1 offset:" OFFSTR                       \
                 : "=v"(dst) : "v"(addr))

// One batch-row chunk: 10 float4 at 16B stride (row is 176B-strided, aligned)
#define DSR10(q, addr)                                                      \
    do {                                                                    \
        DSR((q)[0], (addr), "0");   DSR((q)[1], (addr), "16");              \
        DSR((q)[2], (addr), "32");  DSR((q)[3], (addr), "48");              \
        DSR((q)[4], (addr), "64");  DSR((q)[5], (addr), "80");              \
        DSR((q)[6], (addr), "96");  DSR((q)[7], (addr), "112");             \
        DSR((q)[8], (addr), "128"); DSR((q)[9], (addr), "144");             \
    } while (0)

#define WAIT_LGKM0()                                                        \
    do {                                                                    \
        asm volatile("s_waitcnt lgkmcnt(0)" ::: "memory");                  \
        __builtin_amdgcn_sched_barrier(0);                                  \
    } while (0)

#define WAIT_VM(N)                                                          \
    asm volatile("s_waitcnt vmcnt(" #N ")" ::: "memory")

// Component extract with compile-time-constant idx (folds after unroll).
__device__ __forceinline__ float f4_at(const float4* b, int idx) {
    const float4 v = b[idx >> 2];
    switch (idx & 3) {
        case 0: return v.x;
        case 1: return v.y;
        case 2: return v.z;
        default: return v.w;
    }
}

// tanh with pre-scaled input: zs = 2*log2(e)*z -> tanh(z); saturates right.
__device__ __forceinline__ float tanh_pre(float zs) {
    float e  = __builtin_exp2f(zs);
    float rc = __builtin_amdgcn_rcpf(e + 1.0f);
    return __builtin_fmaf(-2.0f, rc, 1.0f);
}

// 8 timesteps for 16 batches on one wave.
// r10 restructure: x-projection MFMAs are hoisted OFF the serial chain.
//   prep (parallel):  b1[s] fragments; xw[s] = W_ih_pad*x_s + bias (8 indep MFMAs)
//   chain (serial):   acc = W_hh*h + xw[s]; h = tanh(acc)  (ONE MFMA on chain)
// Key invariant (verified r9, absmax 0.0039): D(row=4g+r) grouping ==
// B(k=4g+i) grouping, so tanh(D) --cvt_pkrtz--> next B frag, zero x-lane moves.
__device__ __forceinline__ void steps8(const float4* __restrict__ q,
                                       h4_t& bh,
                                       h4_t ahh, h4_t aih, f4v cbias) {
    // ---- off-chain: B1 fragments for all 8 steps (batched extraction) ----
    h4_t b1[8];
#pragma unroll
    for (int s = 0; s < 8; ++s) {
        const float e0 = f4_at(q, 5 * s + 0);
        const float e1 = f4_at(q, 5 * s + 1);
        const float e2 = f4_at(q, 5 * s + 2);
        const float e3 = f4_at(q, 5 * s + 3);
        h2_t lo = __builtin_amdgcn_cvt_pkrtz(e0, e1);
        h2_t hi = __builtin_amdgcn_cvt_pkrtz(e2, e3);
        b1[s] = __builtin_shufflevector(lo, hi, 0, 1, 2, 3);
    }

    // ---- off-chain: 8 independent x-projection MFMAs (pipeline at rate) ---
    f4v xw[8];
#pragma unroll
    for (int s = 0; s < 8; ++s)
        xw[s] = __builtin_amdgcn_mfma_f32_16x16x16f16(aih, b1[s], cbias,
                                                      0, 0, 0);

    // ---- serial chain: one MFMA + tanh + cvt per step ---------------------
#pragma unroll
    for (int s = 0; s < 8; ++s) {
        f4v acc = __builtin_amdgcn_mfma_f32_16x16x16f16(ahh, bh, xw[s],
                                                        0, 0, 0);
        const float t0 = tanh_pre(acc[0]);
        const float t1 = tanh_pre(acc[1]);
        const float t2 = tanh_pre(acc[2]);
        const float t3 = tanh_pre(acc[3]);
        h2_t blo = __builtin_amdgcn_cvt_pkrtz(t0, t1);
        h2_t bhi = __builtin_amdgcn_cvt_pkrtz(t2, t3);
        bh = __builtin_shufflevector(blo, bhi, 0, 1, 2, 3);
    }
}

__global__ __launch_bounds__(64) void rnn_m2o_kernel(
    const float* __restrict__ x, const float* __restrict__ W_ih,
    const float* __restrict__ W_hh, const float* __restrict__ b_ih,
    const float* __restrict__ b_hh, const float* __restrict__ W_fc,
    const float* __restrict__ b_fc, float* __restrict__ out)
{
    const int lane = threadIdx.x;      // one wave per block
    const int g    = lane >> 4;        // lane-group 0..3
    const int bcol = lane & 15;        // batch column (n of B/D), A row (m)
    const int bb   = blockIdx.x * 16;  // first batch of this wave

    // 4 slots x (16 batches x 44 dwords + DMA-dump pad) = 4 x 3072 B
    __shared__ float lds[4 * 768];

    // Fold tanh's 2*log2(e) input scale into all pre-activation weights.
    const float SC = 2.8853900817779268f;

    // MFMA fragments (A: m=lane&15, k=4g+i ; C/D: n=lane&15, row=4g+r)
    h4_t ahh, aih;
    f4v  cbias, wfc4;
#pragma unroll
    for (int i = 0; i < 4; ++i) {
        const int k = 4 * g + i;
        ahh[i]   = (__fp16)(W_hh[bcol * 16 + k] * SC);
        aih[i]   = (__fp16)((k < I_LEN) ? W_ih[bcol * I_LEN + k] * SC : 0.0f);
        cbias[i] = (b_ih[k] + b_hh[k]) * SC;
        wfc4[i]  = W_fc[k];
    }
    const float bfc = b_fc[0];

    // Staging map: slot index s = 64L + lane; s = 11*b + i (i=0..9 real f4,
    // i=10 pad). Linear lane*16B DMA writes land batch b at dword 44b (+4i).
    const float* gsrc[3];
#pragma unroll
    for (int L = 0; L < 3; ++L) {
        const int s = 64 * L + lane;
        const int sb = s / 11, si = s % 11;
        const bool real = (s < 176) && (si < 10);
        gsrc[L] = x + (size_t)(bb + (real ? sb : 0)) * (T_LEN * I_LEN)
                    + (real ? si * 4 : 0);
    }

#define STAGE(n_, slot_)                                                    \
    do {                                                                    \
        const int off_ = (n_) * (CHUNK * I_LEN);                            \
        gload_lds16(gsrc[0] + off_, &lds[(slot_) * 768 + 0]);               \
        gload_lds16(gsrc[1] + off_, &lds[(slot_) * 768 + 256]);             \
        gload_lds16(gsrc[2] + off_, &lds[(slot_) * 768 + 512]);             \
    } while (0)

    // Read base: my batch row (176B stride); odd groups +16B (x4-shift).
    const uint32_t rbase = (uint32_t)(uintptr_t)&lds[0]
                         + (uint32_t)(bcol * 176 + (g & 1) * 16);

    h4_t bh = (h4_t)0;                 // h_0 = 0 (f16 B fragment)
    float4 qA[10], qB[10];

    // Prologue: stage chunks 0..2, read chunk 0.
    STAGE(0, 0); STAGE(1, 1); STAGE(2, 2);
    WAIT_VM(6);                        // chunk 0 landed
    DSR10(qA, rbase);
    WAIT_LGKM0();

    for (int n = 0; n < NCHUNK; n += 2) {
        {   // even: compute chunk n (qA), prefetch-read chunk n+1
            STAGE((n + 3) & (NCHUNK - 1), (n + 3) & 3);
            WAIT_VM(6);                // chunk n+1 landed
            DSR10(qB, rbase + (uint32_t)(((n + 1) & 3) * 3072));
            steps8(qA, bh, ahh, aih, cbias);
            WAIT_LGKM0();
        }
        {   // odd: compute chunk n+1 (qB), prefetch-read chunk n+2
            STAGE((n + 4) & (NCHUNK - 1), (n + 4) & 3);
            WAIT_VM(6);                // chunk n+2 landed
            DSR10(qA, rbase + (uint32_t)(((n + 2) & 3) * 3072));
            steps8(qB, bh, ahh, aih, cbias);
            WAIT_LGKM0();
        }
    }
    WAIT_VM(0);                        // drain tail DMAs

    // fc + sigmoid: unpack final h from the f16 B fragment (same values the
    // recurrence itself consumed), lane partial, then sum the 4 lane-groups.
    float p = (float)bh[0] * wfc4[0] + (float)bh[1] * wfc4[1]
            + (float)bh[2] * wfc4[2] + (float)bh[3] * wfc4[3];
    p += __shfl_xor(p, 16);
    p += __shfl_xor(p, 32);
    if (lane < 16) {
        const float z = p + bfc;
        out[bb + lane] = __builtin_amdgcn_rcpf(
            1.0f + __builtin_exp2f(z * -1.4426950408889634f));
    }
#undef STAGE
}

extern "C" void kernel_launch(void* const* d_in, const int* in_sizes, int n_in,
                              void* d_out, int out_size, void* d_ws, size_t ws_size,
                              hipStream_t stream) {
    const float* x    = (const float*)d_in[0];
    const float* W_ih = (const float*)d_in[1];
    const float* W_hh = (const float*)d_in[2];
    const float* b_ih = (const float*)d_in[3];
    const float* b_hh = (const float*)d_in[4];
    const float* W_fc = (const float*)d_in[5];
    const float* b_fc = (const float*)d_in[6];
    float* out = (float*)d_out;

    const int B = in_sizes[0] / (T_LEN * I_LEN);   // 8192
    const int blocks = B / 16;                     // 16 batches per wave
    rnn_m2o_kernel<<<blocks, 64, 0, stream>>>(x, W_ih, W_hh, b_ih, b_hh,
                                              W_fc, b_fc, out);
}